// Round 1
// baseline (203.712 us; speedup 1.0000x reference)
//
#include <hip/hip_runtime.h>

// LIF SNN, 50 timesteps x 8192 neurons.
//   FF[t][j] = sum_k x[t][k] * w_in[j][k]   (batched GEMM, w_in read ONCE)
//   then a sequential 50-step scan on a single CU with event-driven recurrence
//   (spike list; w_rec columns only gathered for neurons that actually spiked).

#define NEUR 8192
#define TSTEPS 50

// ---------------- K1: feed-forward GEMM (K-split partials) ----------------
#define BT 64            // t-tile (50 padded to 64)
#define BJ 128           // j-tile
#define BK 64            // k-step
#define KSPLIT 8
#define KCHUNK (NEUR / KSPLIT)   // 1024
#define NKSTEP (KCHUNK / BK)     // 16
#define GTHREADS 256
#define WSTR 130         // LDS row stride for W  [k][j] (pad: 4-way max on writes)
#define XSTR 66          // LDS row stride for X  [k][t]

__global__ __launch_bounds__(GTHREADS, 2)
void ff_gemm(const float* __restrict__ x,   // [50][8192]
             const float* __restrict__ w,   // [8192][8192]
             float* __restrict__ P)         // [KSPLIT][50][8192] partials
{
    __shared__ float Wl[BK * WSTR];
    __shared__ float Xl[BK * XSTR];
    const int tid = threadIdx.x;
    const int jt  = blockIdx.x & 63;    // 64 j-tiles
    const int ks  = blockIdx.x >> 6;    // 8 k-splits
    const int j0  = jt * BJ;
    const int k0  = ks * KCHUNK;
    const int ji  = tid & 15;           // 16 j-positions (2 strips of 4)
    const int ti  = tid >> 4;           // 16 t-positions (4 each)

    float acc[4][8];
#pragma unroll
    for (int m = 0; m < 4; ++m)
#pragma unroll
        for (int n = 0; n < 8; ++n) acc[m][n] = 0.f;

    float4 wst[8], xst[4];              // register staging (double buffer)

    // prefetch tile 0
    {
        const int kc = k0;
#pragma unroll
        for (int it = 0; it < 8; ++it) {
            const int flat = it * GTHREADS + tid;
            const int r = flat >> 4, c4 = flat & 15;
            wst[it] = *(const float4*)&w[(size_t)(j0 + r) * NEUR + kc + c4 * 4];
        }
#pragma unroll
        for (int it = 0; it < 4; ++it) {
            const int flat = it * GTHREADS + tid;
            const int t = flat >> 4, c4 = flat & 15;
            xst[it] = (t < TSTEPS)
                ? *(const float4*)&x[(size_t)t * NEUR + kc + c4 * 4]
                : make_float4(0.f, 0.f, 0.f, 0.f);
        }
    }

    for (int kk = 0; kk < NKSTEP; ++kk) {
        __syncthreads();                         // prev tile's consumers done
        // staged regs -> LDS, transposed ([k][j] / [k][t])
#pragma unroll
        for (int it = 0; it < 8; ++it) {
            const int flat = it * GTHREADS + tid;
            const int r = flat >> 4, c4 = flat & 15;
            const float4 vv = wst[it];
            Wl[(c4 * 4 + 0) * WSTR + r] = vv.x;
            Wl[(c4 * 4 + 1) * WSTR + r] = vv.y;
            Wl[(c4 * 4 + 2) * WSTR + r] = vv.z;
            Wl[(c4 * 4 + 3) * WSTR + r] = vv.w;
        }
#pragma unroll
        for (int it = 0; it < 4; ++it) {
            const int flat = it * GTHREADS + tid;
            const int t = flat >> 4, c4 = flat & 15;
            const float4 vv = xst[it];
            Xl[(c4 * 4 + 0) * XSTR + t] = vv.x;
            Xl[(c4 * 4 + 1) * XSTR + t] = vv.y;
            Xl[(c4 * 4 + 2) * XSTR + t] = vv.z;
            Xl[(c4 * 4 + 3) * XSTR + t] = vv.w;
        }
        __syncthreads();
        // prefetch next tile into regs; HBM latency hides under the FMAs below
        if (kk + 1 < NKSTEP) {
            const int kc = k0 + (kk + 1) * BK;
#pragma unroll
            for (int it = 0; it < 8; ++it) {
                const int flat = it * GTHREADS + tid;
                const int r = flat >> 4, c4 = flat & 15;
                wst[it] = *(const float4*)&w[(size_t)(j0 + r) * NEUR + kc + c4 * 4];
            }
#pragma unroll
            for (int it = 0; it < 4; ++it) {
                const int flat = it * GTHREADS + tid;
                const int t = flat >> 4, c4 = flat & 15;
                xst[it] = (t < TSTEPS)
                    ? *(const float4*)&x[(size_t)t * NEUR + kc + c4 * 4]
                    : make_float4(0.f, 0.f, 0.f, 0.f);
            }
        }
        // compute: 4t x 8j per thread (j = two strips of 4, 64 apart)
#pragma unroll 4
        for (int k = 0; k < BK; ++k) {
            const float* xr = &Xl[k * XSTR + ti * 4];
            const float2 a01 = *(const float2*)(xr);
            const float2 a23 = *(const float2*)(xr + 2);
            const float* wr = &Wl[k * WSTR + ji * 4];
            const float2 b01 = *(const float2*)(wr);
            const float2 b23 = *(const float2*)(wr + 2);
            const float2 b45 = *(const float2*)(wr + 64);
            const float2 b67 = *(const float2*)(wr + 66);
            const float a[4] = {a01.x, a01.y, a23.x, a23.y};
            const float b[8] = {b01.x, b01.y, b23.x, b23.y,
                                b45.x, b45.y, b67.x, b67.y};
#pragma unroll
            for (int m = 0; m < 4; ++m)
#pragma unroll
                for (int n = 0; n < 8; ++n)
                    acc[m][n] = fmaf(a[m], b[n], acc[m][n]);
        }
    }

    // write K-split partial (only real t rows)
#pragma unroll
    for (int m = 0; m < 4; ++m) {
        const int t = ti * 4 + m;
        if (t < TSTEPS) {
            const size_t base = ((size_t)ks * TSTEPS + t) * NEUR + j0 + ji * 4;
            *(float4*)&P[base]      = make_float4(acc[m][0], acc[m][1], acc[m][2], acc[m][3]);
            *(float4*)&P[base + 64] = make_float4(acc[m][4], acc[m][5], acc[m][6], acc[m][7]);
        }
    }
}

// ---------------- K2: reduce K-split partials -> FF ----------------
__global__ __launch_bounds__(256)
void reduce_p(const float4* __restrict__ P, float4* __restrict__ FF)
{
    const int i = blockIdx.x * 256 + threadIdx.x;       // < 102400
    const int stride = TSTEPS * NEUR / 4;
    if (i >= stride) return;
    float4 s = P[i];
#pragma unroll
    for (int sd = 1; sd < KSPLIT; ++sd) {
        const float4 p = P[(size_t)sd * stride + i];
        s.x += p.x; s.y += p.y; s.z += p.z; s.w += p.w;
    }
    FF[i] = s;
}

// ---------------- K3: sequential LIF scan, one block, event-driven ----------------
__global__ __launch_bounds__(1024)
void lif_scan(const float* __restrict__ FF,     // [50][8192]
              const float* __restrict__ wrec,   // [8192][8192]
              float* __restrict__ out)          // [50][8192]
{
    const int tid = threadIdx.x;
    __shared__ unsigned short list[2][NEUR];    // double-buffered spike lists
    __shared__ int cnt[2];

    float v[8], cur[8];
#pragma unroll
    for (int n = 0; n < 8; ++n) { v[n] = -70.0f; cur[n] = 0.0f; }
    if (tid == 0) { cnt[0] = 0; cnt[1] = 0; }

    const float A = 5.0e-5f;   // DT * TAU_MEM_INV
    const float B = 1.0e-4f;   // DT * TAU_SYN_INV
    const float V_LEAK = -70.0f, V_TH = -55.0f, V_RESET = -70.0f;

    for (int t = 0; t < TSTEPS; ++t) {
        const int rb = t & 1, wb = rb ^ 1;
        __syncthreads();                     // B1: prev appends + reads settled
        if (tid == 0) cnt[wb] = 0;
        __syncthreads();                     // B2: reset visible before appends

        // recurrent current from PREVIOUS step's spikes (carry z)
        float rec[8];
#pragma unroll
        for (int n = 0; n < 8; ++n) rec[n] = 0.0f;
        const int c = cnt[rb];
        for (int s = 0; s < c; ++s) {
            const int k = list[rb][s];
#pragma unroll
            for (int n = 0; n < 8; ++n)
                rec[n] += wrec[(size_t)(tid + n * 1024) * NEUR + k];
        }

        // feedforward current for this step
        float ff[8];
#pragma unroll
        for (int n = 0; n < 8; ++n)
            ff[n] = FF[(size_t)t * NEUR + tid + n * 1024];

        // LIF update (exact reference order)
#pragma unroll
        for (int n = 0; n < 8; ++n) {
            const float vd = v[n] + A * ((V_LEAK - v[n]) + cur[n]);
            const float id = cur[n] - B * cur[n];
            const bool  sp = vd > V_TH;                 // heaviside(vd - V_TH)
            const float z  = sp ? 1.0f : 0.0f;
            v[n]   = sp ? V_RESET : vd;
            cur[n] = id + ff[n] + rec[n];
            out[(size_t)t * NEUR + tid + n * 1024] = z;
            if (sp) {
                const int pos = atomicAdd(&cnt[wb], 1);
                list[wb][pos] = (unsigned short)(tid + n * 1024);
            }
        }
    }
}

extern "C" void kernel_launch(void* const* d_in, const int* in_sizes, int n_in,
                              void* d_out, int out_size, void* d_ws, size_t ws_size,
                              hipStream_t stream) {
    const float* x     = (const float*)d_in[0];   // spikes_in [50][8192]
    const float* w_in  = (const float*)d_in[1];   // [8192][8192]
    const float* w_rec = (const float*)d_in[2];   // [8192][8192]
    float* out = (float*)d_out;

    float* P  = (float*)d_ws;                         // 8*50*8192 f32 = 13.1 MB
    float* FF = P + (size_t)KSPLIT * TSTEPS * NEUR;   // 50*8192 f32 = 1.6 MB

    ff_gemm <<<dim3((NEUR / BJ) * KSPLIT), dim3(GTHREADS), 0, stream>>>(x, w_in, P);
    reduce_p<<<dim3(TSTEPS * NEUR / 4 / 256), dim3(256), 0, stream>>>((const float4*)P, (float4*)FF);
    lif_scan<<<dim3(1), dim3(1024), 0, stream>>>(FF, w_rec, out);
}

// Round 2
// 84.805 us; speedup vs baseline: 2.4021x; 2.4021x over previous
//
#include <hip/hip_runtime.h>

// LIF SNN, 50 timesteps x 8192 neurons.
// 1) prep:          x f32 -> bf16 (padded to 64 t), zero FF + spike flag
// 2) ff_gemm_mfma:  FF[t][j] = sum_k x[t][k]*w_in[j][k] via bf16 MFMA,
//                   w_in streamed f32->reg->cvt (no LDS), K-split 16,
//                   f32 atomicAdd into FF
// 3) spec_scan:     per-neuron parallel scan assuming no spikes (true for
//                   this parameterization: threshold margin ~15 units);
//                   flags if any spike occurred
// 4) lif_fallback:  exact sequential event-driven scan, runs only if flagged

#define NEUR 8192
#define TSTEPS 50
#define TPAD 64

typedef __attribute__((ext_vector_type(8))) short bs8;   // 8 bf16 (4 VGPR)
typedef __attribute__((ext_vector_type(4))) float fx4;   // MFMA C/D

static __device__ __forceinline__ unsigned short f2b(float f) {
    // f32 -> bf16 round-to-nearest-even
    unsigned u = __float_as_uint(f);
    return (unsigned short)((u + 0x7FFFu + ((u >> 16) & 1u)) >> 16);
}

// ---------------- K0: convert x, zero FF + flag ----------------
__global__ __launch_bounds__(256)
void prep(const float* __restrict__ x, unsigned short* __restrict__ xb,
          float* __restrict__ FF, int* __restrict__ flag)
{
    const int e = blockIdx.x * 256 + threadIdx.x;    // < TPAD*NEUR
    const int t = e >> 13;
    xb[e] = (t < TSTEPS) ? f2b(x[e]) : (unsigned short)0;
    if (e < TSTEPS * NEUR) FF[e] = 0.f;
    if (e == 0) *flag = 0;
}

// ---------------- K1: feed-forward GEMM via bf16 MFMA ----------------
// grid = 64 j-blocks (128 j each) x 16 k-splits; block = 4 waves.
// wave -> 32 j (2 MFMA col-tiles) x 64 t x 512 k.
#define KSPLIT 16
#define KCHUNK (NEUR / KSPLIT)    // 512
#define NKSTEP (KCHUNK / 32)      // 16

__global__ __launch_bounds__(256)
void ff_gemm_mfma(const float* __restrict__ w,            // [8192][8192]
                  const unsigned short* __restrict__ xb,  // [64][8192] bf16 bits
                  float* __restrict__ FF)                 // [50][8192]
{
    const int wv   = threadIdx.x >> 6;
    const int lane = threadIdx.x & 63;
    const int jb   = blockIdx.x & 63;     // 64 j-blocks
    const int ks   = blockIdx.x >> 6;     // 16 k-splits
    const int j0   = jb * 128 + wv * 32;
    const int k0   = ks * KCHUNK;
    const int lrow = lane & 15;           // free-dim index within fragment
    const int lgrp = lane >> 4;           // k-group (0..3), 8 k each

    fx4 acc[2][4];
#pragma unroll
    for (int jt = 0; jt < 2; ++jt)
#pragma unroll
        for (int tb = 0; tb < 4; ++tb)
            acc[jt][tb] = (fx4){0.f, 0.f, 0.f, 0.f};

    const unsigned short* xp = xb + (size_t)lrow * NEUR + k0 + lgrp * 8;
    const float* wpa = w + (size_t)(j0 + lrow) * NEUR + k0 + lgrp * 8;
    const float* wpb = wpa + (size_t)16 * NEUR;

#pragma unroll 2
    for (int kk = 0; kk < NKSTEP; ++kk) {
        const int ko = kk * 32;
        // A fragments: 4 t-blocks of 16, each lane 8 contiguous bf16 (16 B)
        const bs8 a0 = *(const bs8*)(xp + ko);
        const bs8 a1 = *(const bs8*)(xp + (size_t)16 * NEUR + ko);
        const bs8 a2 = *(const bs8*)(xp + (size_t)32 * NEUR + ko);
        const bs8 a3 = *(const bs8*)(xp + (size_t)48 * NEUR + ko);
        // B fragments: 2 j-tiles, each lane 8 contiguous f32 (32 B), cvt->bf16
        const float4 wa0 = *(const float4*)(wpa + ko);
        const float4 wa1 = *(const float4*)(wpa + ko + 4);
        const float4 wb0 = *(const float4*)(wpb + ko);
        const float4 wb1 = *(const float4*)(wpb + ko + 4);
        const bs8 b0 = {(short)f2b(wa0.x), (short)f2b(wa0.y), (short)f2b(wa0.z), (short)f2b(wa0.w),
                        (short)f2b(wa1.x), (short)f2b(wa1.y), (short)f2b(wa1.z), (short)f2b(wa1.w)};
        const bs8 b1 = {(short)f2b(wb0.x), (short)f2b(wb0.y), (short)f2b(wb0.z), (short)f2b(wb0.w),
                        (short)f2b(wb1.x), (short)f2b(wb1.y), (short)f2b(wb1.z), (short)f2b(wb1.w)};

        acc[0][0] = __builtin_amdgcn_mfma_f32_16x16x32_bf16(a0, b0, acc[0][0], 0, 0, 0);
        acc[0][1] = __builtin_amdgcn_mfma_f32_16x16x32_bf16(a1, b0, acc[0][1], 0, 0, 0);
        acc[0][2] = __builtin_amdgcn_mfma_f32_16x16x32_bf16(a2, b0, acc[0][2], 0, 0, 0);
        acc[0][3] = __builtin_amdgcn_mfma_f32_16x16x32_bf16(a3, b0, acc[0][3], 0, 0, 0);
        acc[1][0] = __builtin_amdgcn_mfma_f32_16x16x32_bf16(a0, b1, acc[1][0], 0, 0, 0);
        acc[1][1] = __builtin_amdgcn_mfma_f32_16x16x32_bf16(a1, b1, acc[1][1], 0, 0, 0);
        acc[1][2] = __builtin_amdgcn_mfma_f32_16x16x32_bf16(a2, b1, acc[1][2], 0, 0, 0);
        acc[1][3] = __builtin_amdgcn_mfma_f32_16x16x32_bf16(a3, b1, acc[1][3], 0, 0, 0);
    }

    // epilogue: C/D layout col = lane&15, row = (lane>>4)*4 + reg (m89-verified)
#pragma unroll
    for (int jt = 0; jt < 2; ++jt) {
        const int j = j0 + jt * 16 + lrow;
#pragma unroll
        for (int tb = 0; tb < 4; ++tb)
#pragma unroll
            for (int i = 0; i < 4; ++i) {
                const int t = tb * 16 + lgrp * 4 + i;
                if (t < TSTEPS)
                    atomicAdd(&FF[(size_t)t * NEUR + j], acc[jt][tb][i]);
            }
    }
}

// ---------------- K2: speculative parallel scan (assumes z == 0) ----------------
__global__ __launch_bounds__(256)
void spec_scan(const float* __restrict__ FF, float* __restrict__ out,
               int* __restrict__ flag)
{
    const int j = blockIdx.x * 256 + threadIdx.x;   // one neuron per thread
    float v = -70.f, cur = 0.f;
    bool any = false;
    float ffn = FF[j];                              // prefetch t=0
    for (int t = 0; t < TSTEPS; ++t) {
        const float ff = ffn;
        if (t + 1 < TSTEPS) ffn = FF[(size_t)(t + 1) * NEUR + j];
        const float vd = v + 5.0e-5f * ((-70.f - v) + cur);
        const float id = cur - 1.0e-4f * cur;
        const bool sp = vd > -55.f;
        any |= sp;
        v = sp ? -70.f : vd;
        cur = id + ff;                              // no recurrence (speculation)
        out[(size_t)t * NEUR + j] = sp ? 1.f : 0.f;
    }
    if (any) atomicAdd(flag, 1);
}

// ---------------- K3: exact event-driven fallback (only if spikes occurred) ----------------
__global__ __launch_bounds__(1024)
void lif_fallback(const float* __restrict__ FF, const float* __restrict__ wrec,
                  float* __restrict__ out, const int* __restrict__ flag)
{
    if (*flag == 0) return;   // speculation was self-consistent -> out is exact

    const int tid = threadIdx.x;
    __shared__ unsigned short list[2][NEUR];
    __shared__ int cnt[2];

    float v[8], cur[8];
#pragma unroll
    for (int n = 0; n < 8; ++n) { v[n] = -70.0f; cur[n] = 0.0f; }
    if (tid == 0) { cnt[0] = 0; cnt[1] = 0; }

    for (int t = 0; t < TSTEPS; ++t) {
        const int rb = t & 1, wb = rb ^ 1;
        __syncthreads();
        if (tid == 0) cnt[wb] = 0;
        __syncthreads();

        float rec[8];
#pragma unroll
        for (int n = 0; n < 8; ++n) rec[n] = 0.0f;
        const int c = cnt[rb];
        for (int s = 0; s < c; ++s) {
            const int k = list[rb][s];
#pragma unroll
            for (int n = 0; n < 8; ++n)
                rec[n] += wrec[(size_t)(tid + n * 1024) * NEUR + k];
        }

#pragma unroll
        for (int n = 0; n < 8; ++n) {
            const float ff = FF[(size_t)t * NEUR + tid + n * 1024];
            const float vd = v[n] + 5.0e-5f * ((-70.0f - v[n]) + cur[n]);
            const float id = cur[n] - 1.0e-4f * cur[n];
            const bool  sp = vd > -55.0f;
            v[n]   = sp ? -70.0f : vd;
            cur[n] = id + ff + rec[n];
            out[(size_t)t * NEUR + tid + n * 1024] = sp ? 1.0f : 0.0f;
            if (sp) {
                const int pos = atomicAdd(&cnt[wb], 1);
                list[wb][pos] = (unsigned short)(tid + n * 1024);
            }
        }
    }
}

extern "C" void kernel_launch(void* const* d_in, const int* in_sizes, int n_in,
                              void* d_out, int out_size, void* d_ws, size_t ws_size,
                              hipStream_t stream) {
    const float* x     = (const float*)d_in[0];   // [50][8192]
    const float* w_in  = (const float*)d_in[1];   // [8192][8192]
    const float* w_rec = (const float*)d_in[2];   // [8192][8192]
    float* out = (float*)d_out;

    // ws layout (all 16B-aligned): FF f32 [50][8192] | xb bf16 [64][8192] | flag
    float* FF = (float*)d_ws;
    unsigned short* xb = (unsigned short*)((char*)d_ws + (size_t)TSTEPS * NEUR * 4);
    int* flag = (int*)((char*)d_ws + (size_t)TSTEPS * NEUR * 4 + (size_t)TPAD * NEUR * 2);

    prep        <<<dim3(TPAD * NEUR / 256), dim3(256), 0, stream>>>(x, xb, FF, flag);
    ff_gemm_mfma<<<dim3(64 * KSPLIT),       dim3(256), 0, stream>>>(w_in, xb, FF);
    spec_scan   <<<dim3(NEUR / 256),        dim3(256), 0, stream>>>(FF, out, flag);
    lif_fallback<<<dim3(1),                 dim3(1024), 0, stream>>>(FF, w_rec, out, flag);
}